// Round 1
// 2520.774 us; speedup vs baseline: 1.0480x; 1.0480x over previous
//
#include <hip/hip_runtime.h>

#define FLAG_RELU 1
#define FLAG_CAUSAL 2
#define FLAG_OUTF32 4

typedef __attribute__((ext_vector_type(4))) float f32x4;
typedef __attribute__((ext_vector_type(8))) short s16x8;
typedef unsigned short u16;

__device__ __forceinline__ float bf2f(u16 u) {
  union { unsigned int i; float f; } x; x.i = ((unsigned int)u) << 16; return x.f;
}
__device__ __forceinline__ u16 f2bf(float f) {
  union { float f; unsigned int i; } x; x.f = f;
  unsigned int r = (x.i + 0x7fffu + ((x.i >> 16) & 1u)) >> 16;
  return (u16)r;
}

// async global->LDS, 16B per lane (wave-uniform LDS base + lane*16)
__device__ __forceinline__ void gl_lds16(const u16* g, u16* l) {
  __builtin_amdgcn_global_load_lds(
      (const __attribute__((address_space(1))) unsigned int*)g,
      (__attribute__((address_space(3))) unsigned int*)l, 16, 0, 0);
}

// C[m,n] = sum_k A[m,k] * Bt[n,k]   (bf16 in, fp32 accum, fp32 or bf16 out)
// Per-batch offsets: off = (z/zdiv)*S1 + (z%zdiv)*S2 for A, B, C.
__global__ __launch_bounds__(256) void gemm_bt(
    const u16* __restrict__ A, const u16* __restrict__ Bt, void* __restrict__ Cv,
    int M, int N, int K, int lda, int ldb, int ldc,
    int zdiv, long aS1, long aS2, long bS1, long bS2, long cS1, long cS2,
    const float* __restrict__ bias, float scale, int flags)
{
  __shared__ u16 As[128][32];   // linear: required by global_load_lds (no pad)
  __shared__ u16 Bs[128][32];
  // ---- bijective XCD-chunk remap (m204) + M-fastest tile order ----
  // M-fastest: 16 consecutive blocks share one B-panel (weight reuse in L2);
  // XCD chunking keeps that group on one XCD's L2.
  int nx = gridDim.x, ny = gridDim.y;
  int nwg = nx * ny;
  int orig = blockIdx.y * nx + blockIdx.x;
  int q = nwg >> 3, r = nwg & 7;
  int xcd = orig & 7, rest = orig >> 3;
  int wgid = (xcd < r ? xcd * (q + 1) : r * (q + 1) + (xcd - r) * q) + rest;
  int tx = wgid / ny, ty = wgid % ny;   // tx: N-tile, ty: M-tile (M fastest)

  int z = blockIdx.z;
  int z1 = z / zdiv, z2 = z % zdiv;
  const u16* Ab = A + z1 * aS1 + z2 * aS2 + (long)ty * 128 * lda;
  const u16* Bb = Bt + z1 * bS1 + z2 * bS2 + (long)tx * 128 * ldb;
  long offC = z1 * cS1 + z2 * cS2;
  int tid = threadIdx.x;
  int lane = tid & 63, wave = tid >> 6;
  int wm = (wave >> 1) << 6, wn = (wave & 1) << 6;  // 2x2 waves, 64x64 each
  int row0 = tid >> 2, cc = (tid & 3) << 3;          // staging: 4 chunks/row
  int fr = lane & 15, fq = (lane >> 4) << 3;         // fragment addressing
  int m0 = ty * 128, n0 = tx * 128;
  f32x4 acc[4][4] = {};
  // causal full-mask tile: every element has c > r -> skip all compute
  bool skip = (flags & FLAG_CAUSAL) && (n0 > m0 + 127);
  if (!skip) {
    const u16* a0p = Ab + (long)row0 * lda + cc;
    const u16* a1p = a0p + 64L * lda;
    const u16* b0p = Bb + (long)row0 * ldb + cc;
    const u16* b1p = b0p + 64L * ldb;
    u16* da0 = &As[0][0] + tid * 8;
    u16* da1 = &As[0][0] + 2048 + tid * 8;
    u16* db0 = &Bs[0][0] + tid * 8;
    u16* db1 = &Bs[0][0] + 2048 + tid * 8;
    for (int k0 = 0; k0 < K; k0 += 32) {
      if (k0) __syncthreads();           // prev tile fully consumed
      gl_lds16(a0p + k0, da0);
      gl_lds16(a1p + k0, da1);
      gl_lds16(b0p + k0, db0);
      gl_lds16(b1p + k0, db1);
      __syncthreads();                   // vmcnt(0) drained before barrier
      s16x8 af[4], bfr[4];
#pragma unroll
      for (int i = 0; i < 4; i++) af[i] = *(const s16x8*)&As[wm + i * 16 + fr][fq];
#pragma unroll
      for (int i = 0; i < 4; i++) bfr[i] = *(const s16x8*)&Bs[wn + i * 16 + fr][fq];
#pragma unroll
      for (int mi = 0; mi < 4; mi++)
#pragma unroll
        for (int ni = 0; ni < 4; ni++)
          acc[mi][ni] = __builtin_amdgcn_mfma_f32_16x16x32_bf16(af[mi], bfr[ni], acc[mi][ni], 0, 0, 0);
    }
  }
  // epilogue: col = lane&15, row = (lane>>4)*4 + j  (m89-verified C/D layout)
  int eq = (lane >> 4) << 2;
  float* Cf = (float*)Cv;
  u16* Ch = (u16*)Cv;
#pragma unroll
  for (int ni = 0; ni < 4; ni++) {
    int c = n0 + wn + ni * 16 + fr;
    if (c >= N) continue;
    float bv = bias ? bias[c] : 0.f;
#pragma unroll
    for (int mi = 0; mi < 4; mi++) {
      int rbase = m0 + wm + mi * 16 + eq;
#pragma unroll
      for (int j = 0; j < 4; j++) {
        int r = rbase + j;
        float v = acc[mi][ni][j] * scale + bv;
        if ((flags & FLAG_RELU) && v < 0.f) v = 0.f;
        if ((flags & FLAG_CAUSAL) && c > r) v = -1e30f;
        long idx = offC + (long)r * ldc + c;
        if (flags & FLAG_OUTF32) Cf[idx] = v; else Ch[idx] = f2bf(v);
      }
    }
  }
}

// dst[c][r] = bf16(src[r][c]), fp32 src; zero-fills dst rows c in [C, Cpad)
__global__ __launch_bounds__(256) void transpose_f2b(
    const float* __restrict__ src, u16* __restrict__ dst,
    int R, int C, int lds_, int ldd, int Cpad, int zdiv,
    long sS1, long sS2, long dS1, long dS2)
{
  __shared__ u16 tile[32][33];
  int z = blockIdx.z;
  const float* s = src + (z / zdiv) * sS1 + (z % zdiv) * sS2;
  u16* d = dst + (z / zdiv) * dS1 + (z % zdiv) * dS2;
  int c0 = blockIdx.x * 32, r0 = blockIdx.y * 32;
  int tx = threadIdx.x & 31, ty = threadIdx.x >> 5;
#pragma unroll
  for (int i = 0; i < 32; i += 8) {
    int r = r0 + ty + i, c = c0 + tx;
    u16 v = 0;
    if (r < R && c < C) v = f2bf(s[(long)r * lds_ + c]);
    tile[ty + i][tx] = v;
  }
  __syncthreads();
#pragma unroll
  for (int i = 0; i < 32; i += 8) {
    int c = c0 + ty + i, r = r0 + tx;
    if (c < Cpad && r < R) d[(long)c * ldd + r] = tile[tx][ty + i];
  }
}

// dst[c][r] = src[r][c], bf16 -> bf16
__global__ __launch_bounds__(256) void transpose_b2b(
    const u16* __restrict__ src, u16* __restrict__ dst,
    int R, int C, int lds_, int ldd, int Cpad, int zdiv,
    long sS1, long sS2, long dS1, long dS2)
{
  __shared__ u16 tile[32][33];
  int z = blockIdx.z;
  const u16* s = src + (z / zdiv) * sS1 + (z % zdiv) * sS2;
  u16* d = dst + (z / zdiv) * dS1 + (z % zdiv) * dS2;
  int c0 = blockIdx.x * 32, r0 = blockIdx.y * 32;
  int tx = threadIdx.x & 31, ty = threadIdx.x >> 5;
#pragma unroll
  for (int i = 0; i < 32; i += 8) {
    int r = r0 + ty + i, c = c0 + tx;
    u16 v = 0;
    if (r < R && c < C) v = s[(long)r * lds_ + c];
    tile[ty + i][tx] = v;
  }
  __syncthreads();
#pragma unroll
  for (int i = 0; i < 32; i += 8) {
    int c = c0 + ty + i, r = r0 + tx;
    if (c < Cpad && r < R) d[(long)c * ldd + r] = tile[tx][ty + i];
  }
}

// in-place softmax over rows of length 1024 (bf16), fp32 math
__global__ __launch_bounds__(256) void softmax_rows(u16* __restrict__ S)
{
  __shared__ float red[8];
  long row = blockIdx.x;
  u16* p = S + row * 1024;
  int tid = threadIdx.x;
  float v[4];
  float mx = -1e30f;
#pragma unroll
  for (int i = 0; i < 4; i++) { v[i] = bf2f(p[tid + i * 256]); mx = fmaxf(mx, v[i]); }
  for (int off = 32; off >= 1; off >>= 1) mx = fmaxf(mx, __shfl_down(mx, off));
  if ((tid & 63) == 0) red[tid >> 6] = mx;
  __syncthreads();
  if (tid == 0) red[4] = fmaxf(fmaxf(red[0], red[1]), fmaxf(red[2], red[3]));
  __syncthreads();
  mx = red[4];
  float sum = 0.f;
#pragma unroll
  for (int i = 0; i < 4; i++) { v[i] = __expf(v[i] - mx); sum += v[i]; }
  for (int off = 32; off >= 1; off >>= 1) sum += __shfl_down(sum, off);
  if ((tid & 63) == 0) red[tid >> 6] = sum;
  __syncthreads();
  if (tid == 0) red[5] = red[0] + red[1] + red[2] + red[3];
  __syncthreads();
  float rs = 1.f / red[5];
#pragma unroll
  for (int i = 0; i < 4; i++) p[tid + i * 256] = f2bf(v[i] * rs);
}

// x = LN(x + d) * g + b; writes fp32 x (residual stream) and bf16 copy xb
__global__ __launch_bounds__(256) void add_ln(
    float* __restrict__ x, const float* __restrict__ d,
    const float* __restrict__ g, const float* __restrict__ b,
    u16* __restrict__ xb)
{
  __shared__ float red[8];
  long base = blockIdx.x * 768L;
  int tid = threadIdx.x;
  float v[3]; float s = 0.f;
#pragma unroll
  for (int i = 0; i < 3; i++) { int k = tid + i * 256; v[i] = x[base + k] + d[base + k]; s += v[i]; }
  for (int off = 32; off >= 1; off >>= 1) s += __shfl_down(s, off);
  if ((tid & 63) == 0) red[tid >> 6] = s;
  __syncthreads();
  if (tid == 0) red[4] = (red[0] + red[1] + red[2] + red[3]) * (1.f / 768.f);
  __syncthreads();
  float mean = red[4];
  float s2 = 0.f;
#pragma unroll
  for (int i = 0; i < 3; i++) { float t = v[i] - mean; s2 += t * t; }
  for (int off = 32; off >= 1; off >>= 1) s2 += __shfl_down(s2, off);
  if ((tid & 63) == 0) red[tid >> 6] = s2;
  __syncthreads();
  if (tid == 0) red[5] = rsqrtf((red[0] + red[1] + red[2] + red[3]) * (1.f / 768.f) + 1e-5f);
  __syncthreads();
  float rstd = red[5];
#pragma unroll
  for (int i = 0; i < 3; i++) {
    int k = tid + i * 256;
    float y = (v[i] - mean) * rstd * g[k] + b[k];
    x[base + k] = y; xb[base + k] = f2bf(y);
  }
}

__global__ __launch_bounds__(256) void embed_kernel(
    const int* __restrict__ idx, const float* __restrict__ tok, const float* __restrict__ pos,
    float* __restrict__ x, u16* __restrict__ xb)
{
  long row = blockIdx.x;
  int t = (int)(row & 1023);
  long tk = idx[row];
  for (int i = threadIdx.x; i < 768; i += 256) {
    float v = tok[tk * 768 + i] + pos[(long)t * 768 + i];
    x[row * 768 + i] = v;
    xb[row * 768 + i] = f2bf(v);
  }
}

extern "C" void kernel_launch(void* const* d_in, const int* in_sizes, int n_in,
                              void* d_out, int out_size, void* d_ws, size_t ws_size,
                              hipStream_t stream)
{
  const int Bb = 2, T = 1024, D = 768, H = 12, L = 6, V = 50257, HS = 64,
            M = 2048, DFF = 3072, NQ = 2304, VP = 50304;
  const int*   idx     = (const int*)d_in[0];
  const float* tok_emb = (const float*)d_in[1];
  const float* pos_emb = (const float*)d_in[2];
  const float* wq      = (const float*)d_in[3];
  const float* wk      = (const float*)d_in[4];
  const float* wv      = (const float*)d_in[5];
  const float* wproj   = (const float*)d_in[6];
  const float* bproj   = (const float*)d_in[7];
  const float* w1      = (const float*)d_in[8];
  const float* b1      = (const float*)d_in[9];
  const float* w2      = (const float*)d_in[10];
  const float* b2      = (const float*)d_in[11];
  const float* ln1g    = (const float*)d_in[12];
  const float* ln1b    = (const float*)d_in[13];
  const float* ln2g    = (const float*)d_in[14];
  const float* ln2b    = (const float*)d_in[15];
  const float* lmw     = (const float*)d_in[16];
  const float* lmb     = (const float*)d_in[17];
  float* out = (float*)d_out;
  (void)in_sizes; (void)n_in; (void)out_size; (void)ws_size;

  char* ws = (char*)d_ws;
  size_t off = 0;
  auto alloc = [&](size_t bytes) -> char* {
    char* p = ws + off; off += (bytes + 255) & ~(size_t)255; return p;
  };
  // persistent across whole call:
  u16* wqkv_t  = (u16*)alloc((size_t)L * NQ * D * 2);
  u16* wproj_t = (u16*)alloc((size_t)L * D * D * 2);
  u16* w1_t    = (u16*)alloc((size_t)L * DFF * D * 2);
  u16* w2_t    = (u16*)alloc((size_t)L * D * DFF * 2);
  float* x     = (float*)alloc((size_t)M * D * 4);
  u16* xb      = (u16*)alloc((size_t)M * D * 2);
  // per-layer scratch (dead by LM-head time):
  char* scratch_base = ws + off;
  u16* qkv     = (u16*)alloc((size_t)M * NQ * 2);
  u16* vt      = (u16*)alloc(((size_t)Bb * H * HS * T + 64 * T) * 2); // +pad for 128-tile overread
  u16* S       = (u16*)alloc((size_t)Bb * H * T * T * 2);
  u16* attn    = (u16*)alloc((size_t)M * D * 2);
  float* tmp   = (float*)alloc((size_t)M * D * 4);
  u16* h1      = (u16*)alloc((size_t)M * DFF * 2);
  // LM-head weight aliases the dead scratch (needs VP*D*2 = 77.3 MB <= 85.1 MB)
  u16* lmw_t   = (u16*)scratch_base;

  dim3 blk(256);
  // ---- weight downcast-transposes (fp32 -> bf16 [N,K] "Bt" form) ----
  {
    long sS1 = (long)H * D * HS, sS2 = (long)D * HS;
    long dS1 = (long)NQ * D,     dS2 = (long)HS * D;
    transpose_f2b<<<dim3(2, 24, L * H), blk, 0, stream>>>(wq, wqkv_t,                     D, HS, HS, D, HS, H, sS1, sS2, dS1, dS2);
    transpose_f2b<<<dim3(2, 24, L * H), blk, 0, stream>>>(wk, wqkv_t + (size_t)D * D,     D, HS, HS, D, HS, H, sS1, sS2, dS1, dS2);
    transpose_f2b<<<dim3(2, 24, L * H), blk, 0, stream>>>(wv, wqkv_t + (size_t)2 * D * D, D, HS, HS, D, HS, H, sS1, sS2, dS1, dS2);
    transpose_f2b<<<dim3(24, 24, L), blk, 0, stream>>>(wproj, wproj_t, D, D, D, D, D, 1, (long)D * D, 0, (long)D * D, 0);
    transpose_f2b<<<dim3(96, 24, L), blk, 0, stream>>>(w1, w1_t, D, DFF, DFF, D, DFF, 1, (long)D * DFF, 0, (long)DFF * D, 0);
    transpose_f2b<<<dim3(24, 96, L), blk, 0, stream>>>(w2, w2_t, DFF, D, D, DFF, D, 1, (long)DFF * D, 0, (long)D * DFF, 0);
  }
  embed_kernel<<<dim3(M), blk, 0, stream>>>(idx, tok_emb, pos_emb, x, xb);

  for (int l = 0; l < L; l++) {
    // QKV (no bias)
    gemm_bt<<<dim3(NQ / 128, M / 128, 1), blk, 0, stream>>>(
        xb, wqkv_t + (size_t)l * NQ * D, qkv, M, NQ, D, D, D, NQ,
        1, 0, 0, 0, 0, 0, 0, nullptr, 1.f, 0);
    // V^T per (b,h): [T,HS] -> [HS,T]
    transpose_b2b<<<dim3(2, 32, Bb * H), blk, 0, stream>>>(
        qkv + 2 * D, vt, T, HS, NQ, T, HS, H,
        (long)T * NQ, (long)HS, (long)H * HS * T, (long)HS * T);
    // scores = Q K^T * 0.125, causal mask, bf16
    gemm_bt<<<dim3(T / 128, T / 128, Bb * H), blk, 0, stream>>>(
        qkv, qkv + D, S, T, T, HS, NQ, NQ, T,
        H, (long)T * NQ, (long)HS, (long)T * NQ, (long)HS, (long)H * T * T, (long)T * T,
        nullptr, 0.125f, FLAG_CAUSAL);
    softmax_rows<<<dim3(Bb * H * T), blk, 0, stream>>>(S);
    // O = P V  (N=64; cols 64..127 of tile masked; vt has padded alloc)
    gemm_bt<<<dim3(1, T / 128, Bb * H), blk, 0, stream>>>(
        S, vt, attn, T, HS, T, T, T, D,
        H, (long)H * T * T, (long)T * T, (long)H * HS * T, (long)HS * T, (long)T * D, (long)HS,
        nullptr, 1.f, 0);
    // proj (+bias) -> fp32 tmp
    gemm_bt<<<dim3(D / 128, M / 128, 1), blk, 0, stream>>>(
        attn, wproj_t + (size_t)l * D * D, tmp, M, D, D, D, D, D,
        1, 0, 0, 0, 0, 0, 0, bproj + (size_t)l * D, 1.f, FLAG_OUTF32);
    add_ln<<<dim3(M), blk, 0, stream>>>(x, tmp, ln1g + (size_t)l * D, ln1b + (size_t)l * D, xb);
    // fc1 (+bias, relu) -> bf16 h1
    gemm_bt<<<dim3(DFF / 128, M / 128, 1), blk, 0, stream>>>(
        xb, w1_t + (size_t)l * DFF * D, h1, M, DFF, D, D, D, DFF,
        1, 0, 0, 0, 0, 0, 0, b1 + (size_t)l * DFF, 1.f, FLAG_RELU);
    // fc2 (+bias) -> fp32 tmp
    gemm_bt<<<dim3(D / 128, M / 128, 1), blk, 0, stream>>>(
        h1, w2_t + (size_t)l * D * DFF, tmp, M, D, DFF, DFF, DFF, D,
        1, 0, 0, 0, 0, 0, 0, b2 + (size_t)l * D, 1.f, FLAG_OUTF32);
    add_ln<<<dim3(M), blk, 0, stream>>>(x, tmp, ln2g + (size_t)l * D, ln2b + (size_t)l * D, xb);
  }
  // LM-head weight transpose into dead scratch ([D,V] fp32 -> [VP,D] bf16, zero-padded rows)
  transpose_f2b<<<dim3(1572, 24, 1), blk, 0, stream>>>(lmw, lmw_t, D, V, V, D, VP, 1, 0, 0, 0, 0);
  // LM head -> fp32 logits
  gemm_bt<<<dim3(VP / 128, M / 128, 1), blk, 0, stream>>>(
      xb, lmw_t, out, M, V, D, D, D, V,
      1, 0, 0, 0, 0, 0, 0, lmb, 1.f, FLAG_OUTF32);
}

// Round 2
// 2253.128 us; speedup vs baseline: 1.1725x; 1.1188x over previous
//
#include <hip/hip_runtime.h>

#define FLAG_RELU 1
#define FLAG_CAUSAL 2
#define FLAG_OUTF32 4

typedef __attribute__((ext_vector_type(4))) float f32x4;
typedef __attribute__((ext_vector_type(8))) short s16x8;
typedef unsigned short u16;

__device__ __forceinline__ float bf2f(u16 u) {
  union { unsigned int i; float f; } x; x.i = ((unsigned int)u) << 16; return x.f;
}
__device__ __forceinline__ u16 f2bf(float f) {
  union { float f; unsigned int i; } x; x.f = f;
  unsigned int r = (x.i + 0x7fffu + ((x.i >> 16) & 1u)) >> 16;
  return (u16)r;
}

// async global->LDS, 16B per lane (wave-uniform LDS base + lane*16)
__device__ __forceinline__ void gl_lds16(const u16* g, u16* l) {
  __builtin_amdgcn_global_load_lds(
      (const __attribute__((address_space(1))) unsigned int*)g,
      (__attribute__((address_space(3))) unsigned int*)l, 16, 0, 0);
}

// C[m,n] = sum_k A[m,k] * Bt[n,k]   (bf16 in, fp32 accum, fp32 or bf16 out)
__global__ __launch_bounds__(256) void gemm_bt(
    const u16* __restrict__ A, const u16* __restrict__ Bt, void* __restrict__ Cv,
    int M, int N, int K, int lda, int ldb, int ldc,
    int zdiv, long aS1, long aS2, long bS1, long bS2, long cS1, long cS2,
    const float* __restrict__ bias, float scale, int flags)
{
  __shared__ u16 As[128][32];   // linear: required by global_load_lds (no pad)
  __shared__ u16 Bs[128][32];
  // bijective XCD-chunk remap (m204) + M-fastest tile order for B-panel L2 reuse
  int nx = gridDim.x, ny = gridDim.y;
  int nwg = nx * ny;
  int orig = blockIdx.y * nx + blockIdx.x;
  int q = nwg >> 3, r = nwg & 7;
  int xcd = orig & 7, rest = orig >> 3;
  int wgid = (xcd < r ? xcd * (q + 1) : r * (q + 1) + (xcd - r) * q) + rest;
  int tx = wgid / ny, ty = wgid % ny;   // tx: N-tile, ty: M-tile (M fastest)

  int z = blockIdx.z;
  int z1 = z / zdiv, z2 = z % zdiv;
  const u16* Ab = A + z1 * aS1 + z2 * aS2 + (long)ty * 128 * lda;
  const u16* Bb = Bt + z1 * bS1 + z2 * bS2 + (long)tx * 128 * ldb;
  long offC = z1 * cS1 + z2 * cS2;
  int tid = threadIdx.x;
  int lane = tid & 63, wave = tid >> 6;
  int wm = (wave >> 1) << 6, wn = (wave & 1) << 6;  // 2x2 waves, 64x64 each
  int row0 = tid >> 2, cc = (tid & 3) << 3;          // staging: 4 chunks/row
  int fr = lane & 15, fq = (lane >> 4) << 3;         // fragment addressing
  int m0 = ty * 128, n0 = tx * 128;
  f32x4 acc[4][4] = {};
  bool skip = (flags & FLAG_CAUSAL) && (n0 > m0 + 127);
  if (!skip) {
    const u16* a0p = Ab + (long)row0 * lda + cc;
    const u16* a1p = a0p + 64L * lda;
    const u16* b0p = Bb + (long)row0 * ldb + cc;
    const u16* b1p = b0p + 64L * ldb;
    u16* da0 = &As[0][0] + tid * 8;
    u16* da1 = &As[0][0] + 2048 + tid * 8;
    u16* db0 = &Bs[0][0] + tid * 8;
    u16* db1 = &Bs[0][0] + 2048 + tid * 8;
    for (int k0 = 0; k0 < K; k0 += 32) {
      if (k0) __syncthreads();
      gl_lds16(a0p + k0, da0);
      gl_lds16(a1p + k0, da1);
      gl_lds16(b0p + k0, db0);
      gl_lds16(b1p + k0, db1);
      __syncthreads();
      s16x8 af[4], bfr[4];
#pragma unroll
      for (int i = 0; i < 4; i++) af[i] = *(const s16x8*)&As[wm + i * 16 + fr][fq];
#pragma unroll
      for (int i = 0; i < 4; i++) bfr[i] = *(const s16x8*)&Bs[wn + i * 16 + fr][fq];
#pragma unroll
      for (int mi = 0; mi < 4; mi++)
#pragma unroll
        for (int ni = 0; ni < 4; ni++)
          acc[mi][ni] = __builtin_amdgcn_mfma_f32_16x16x32_bf16(af[mi], bfr[ni], acc[mi][ni], 0, 0, 0);
    }
  }
  // epilogue: col = lane&15, row = (lane>>4)*4 + j  (m89-verified C/D layout)
  int eq = (lane >> 4) << 2;
  float* Cf = (float*)Cv;
  u16* Ch = (u16*)Cv;
#pragma unroll
  for (int ni = 0; ni < 4; ni++) {
    int c = n0 + wn + ni * 16 + fr;
    if (c >= N) continue;
    float bv = bias ? bias[c] : 0.f;
#pragma unroll
    for (int mi = 0; mi < 4; mi++) {
      int rbase = m0 + wm + mi * 16 + eq;
#pragma unroll
      for (int j = 0; j < 4; j++) {
        int r = rbase + j;
        float v = acc[mi][ni][j] * scale + bv;
        if ((flags & FLAG_RELU) && v < 0.f) v = 0.f;
        if ((flags & FLAG_CAUSAL) && c > r) v = -1e30f;
        long idx = offC + (long)r * ldc + c;
        if (flags & FLAG_OUTF32) Cf[idx] = v; else Ch[idx] = f2bf(v);
      }
    }
  }
}

// Fused causal flash attention: B=2,H=12,T=1024,HS=64.
// qkv rows [2048][2304]: Q at +0, K at +768, V at +1536 (per-head h*64).
// Block = (qtile 64 rows, bh). 4 waves; wave w owns q rows [w*16, w*16+16).
__global__ __launch_bounds__(256) void flash_attn(
    const u16* __restrict__ qkv, u16* __restrict__ attn)
{
  __shared__ u16 QL[4096];        // [kc2][64 q][32 d] linear
  __shared__ u16 KL[4096];        // [kc2][64 kv][32 d] linear
  __shared__ u16 VtL[4096];       // [kc2][64 hs][32 kv], XOR-swizzled by (hs>>4)
  __shared__ u16 PL[4 * 16 * 72]; // per-wave P [16 q][72], stride 72 (16B-aligned rows)
  const int NQ = 2304, D = 768, T = 1024;
  int qt = blockIdx.x, bh = blockIdx.y;
  int b = bh / 12, h = bh - b * 12;
  int q0 = qt * 64;
  int tid = threadIdx.x;
  int lane = tid & 63, w = tid >> 6;
  int fr = lane & 15, g = lane >> 4;
  int eq = g << 2, fq = g << 3;
  const u16* base = qkv + (long)(b * T) * NQ + h * 64;
  const u16* Qg = base + (long)q0 * NQ;
  const u16* Kg = base + 768;
  const u16* Vg = base + 1536;
  int srow = tid >> 2, scol = (tid & 3) << 3;   // staging map: row 0..63, col-chunk
  int hs0 = (tid & 3) << 4;                      // V load: 16 hs per thread
  // stage Q once: LDS elem off = c*2048 + tid*8 -> (kc=c, row=tid>>2, col=(tid&3)*8)
#pragma unroll
  for (int c = 0; c < 2; c++)
    gl_lds16(Qg + (long)srow * NQ + c * 32 + scol, QL + c * 2048 + tid * 8);
  f32x4 oacc[4] = {};
  f32x4 m, sml;
#pragma unroll
  for (int j = 0; j < 4; j++) { m[j] = -1e30f; sml[j] = 0.f; }
  int nt = qt + 1;
  for (int t = 0; t < nt; t++) {
    const u16* Kt = Kg + (long)(t * 64) * NQ;
    const u16* Vt = Vg + (long)(t * 64) * NQ;
    __syncthreads();   // prev tile fully consumed; Q staged (vmcnt drains at barrier)
#pragma unroll
    for (int c = 0; c < 2; c++)
      gl_lds16(Kt + (long)srow * NQ + c * 32 + scol, KL + c * 2048 + tid * 8);
    // V: reg load (coalesced) + transposed swizzled LDS write
    s16x8 v0 = *(const s16x8*)(Vt + (long)srow * NQ + hs0);
    s16x8 v1 = *(const s16x8*)(Vt + (long)srow * NQ + hs0 + 8);
    int kc = srow >> 5, kvc = srow & 31;
#pragma unroll
    for (int i = 0; i < 16; i++) {
      u16 val = (u16)(i < 8 ? v0[i] : v1[i - 8]);
      int hs = hs0 + i;
      int off = kc * 2048 + hs * 32 + kvc;
      int byt = (off * 2) ^ (((hs >> 4) & 3) << 4);
      *(u16*)((char*)VtL + byt) = val;
    }
    __syncthreads();   // K staged + Vt visible
    // S = Q K^T (f32), wave-tile [16 q][64 kv]
    f32x4 sf[4] = {};
#pragma unroll
    for (int kst = 0; kst < 2; kst++) {
      s16x8 aq = *(const s16x8*)(QL + kst * 2048 + (w * 16 + fr) * 32 + fq);
#pragma unroll
      for (int ni = 0; ni < 4; ni++) {
        s16x8 bk = *(const s16x8*)(KL + kst * 2048 + (ni * 16 + fr) * 32 + fq);
        sf[ni] = __builtin_amdgcn_mfma_f32_16x16x32_bf16(aq, bk, sf[ni], 0, 0, 0);
      }
    }
    // scale + causal mask (diagonal tile only)
    bool diag = (t == qt);
#pragma unroll
    for (int ni = 0; ni < 4; ni++)
#pragma unroll
      for (int j = 0; j < 4; j++) {
        float s = sf[ni][j] * 0.125f;
        if (diag && (ni * 16 + fr > w * 16 + eq + j)) s = -1e30f;
        sf[ni][j] = s;
      }
    // row max over kv: in-lane over ni, then across the 16-lane fr group
    f32x4 rm = sf[0];
#pragma unroll
    for (int ni = 1; ni < 4; ni++)
#pragma unroll
      for (int j = 0; j < 4; j++) rm[j] = fmaxf(rm[j], sf[ni][j]);
#pragma unroll
    for (int o = 1; o <= 8; o <<= 1)
#pragma unroll
      for (int j = 0; j < 4; j++) rm[j] = fmaxf(rm[j], __shfl_xor(rm[j], o));
    f32x4 mn, corr;
#pragma unroll
    for (int j = 0; j < 4; j++) {
      mn[j] = fmaxf(m[j], rm[j]);
      corr[j] = __expf(m[j] - mn[j]);
      m[j] = mn[j];
    }
    f32x4 rs;
#pragma unroll
    for (int j = 0; j < 4; j++) rs[j] = 0.f;
#pragma unroll
    for (int ni = 0; ni < 4; ni++)
#pragma unroll
      for (int j = 0; j < 4; j++) {
        float p = __expf(sf[ni][j] - mn[j]);
        sf[ni][j] = p;
        rs[j] += p;
      }
#pragma unroll
    for (int o = 1; o <= 8; o <<= 1)
#pragma unroll
      for (int j = 0; j < 4; j++) rs[j] += __shfl_xor(rs[j], o);
#pragma unroll
    for (int j = 0; j < 4; j++) sml[j] = sml[j] * corr[j] + rs[j];
#pragma unroll
    for (int ni = 0; ni < 4; ni++)
#pragma unroll
      for (int j = 0; j < 4; j++) oacc[ni][j] *= corr[j];
    // P -> wave-local LDS (bf16), C-layout scatter; stride 72 keeps 16B rows
    u16* Pw = PL + w * 1152;
#pragma unroll
    for (int ni = 0; ni < 4; ni++)
#pragma unroll
      for (int j = 0; j < 4; j++)
        Pw[(eq + j) * 72 + ni * 16 + fr] = f2bf(sf[ni][j]);
    // O += P V  (A = P rows q=fr, k=kv; B = Vt rows hs, k=kv)
#pragma unroll
    for (int kst = 0; kst < 2; kst++) {
      s16x8 ap = *(const s16x8*)(Pw + fr * 72 + kst * 32 + fq);
#pragma unroll
      for (int ni = 0; ni < 4; ni++) {
        int off = kst * 2048 + (ni * 16 + fr) * 32 + fq;
        int byt = (off * 2) ^ ((ni & 3) << 4);
        s16x8 bv = *(const s16x8*)((const char*)VtL + byt);
        oacc[ni] = __builtin_amdgcn_mfma_f32_16x16x32_bf16(ap, bv, oacc[ni], 0, 0, 0);
      }
    }
  }
  // epilogue: O / l, bf16 store (C-layout: hs = ni*16+fr, q = eq+j)
  f32x4 rl;
#pragma unroll
  for (int j = 0; j < 4; j++) rl[j] = 1.f / sml[j];
  u16* Og = attn + (long)(b * T + q0 + w * 16) * D + h * 64;
#pragma unroll
  for (int ni = 0; ni < 4; ni++)
#pragma unroll
    for (int j = 0; j < 4; j++)
      Og[(long)(eq + j) * D + ni * 16 + fr] = f2bf(oacc[ni][j] * rl[j]);
}

// dst[c][r] = bf16(src[r][c]), fp32 src; zero-fills dst rows c in [C, Cpad)
__global__ __launch_bounds__(256) void transpose_f2b(
    const float* __restrict__ src, u16* __restrict__ dst,
    int R, int C, int lds_, int ldd, int Cpad, int zdiv,
    long sS1, long sS2, long dS1, long dS2)
{
  __shared__ u16 tile[32][33];
  int z = blockIdx.z;
  const float* s = src + (z / zdiv) * sS1 + (z % zdiv) * sS2;
  u16* d = dst + (z / zdiv) * dS1 + (z % zdiv) * dS2;
  int c0 = blockIdx.x * 32, r0 = blockIdx.y * 32;
  int tx = threadIdx.x & 31, ty = threadIdx.x >> 5;
#pragma unroll
  for (int i = 0; i < 32; i += 8) {
    int r = r0 + ty + i, c = c0 + tx;
    u16 v = 0;
    if (r < R && c < C) v = f2bf(s[(long)r * lds_ + c]);
    tile[ty + i][tx] = v;
  }
  __syncthreads();
#pragma unroll
  for (int i = 0; i < 32; i += 8) {
    int c = c0 + ty + i, r = r0 + tx;
    if (c < Cpad && r < R) d[(long)c * ldd + r] = tile[tx][ty + i];
  }
}

// x = LN(x + d) * g + b; writes fp32 x (residual stream) and bf16 copy xb
__global__ __launch_bounds__(256) void add_ln(
    float* __restrict__ x, const float* __restrict__ d,
    const float* __restrict__ g, const float* __restrict__ b,
    u16* __restrict__ xb)
{
  __shared__ float red[8];
  long base = blockIdx.x * 768L;
  int tid = threadIdx.x;
  float v[3]; float s = 0.f;
#pragma unroll
  for (int i = 0; i < 3; i++) { int k = tid + i * 256; v[i] = x[base + k] + d[base + k]; s += v[i]; }
  for (int off = 32; off >= 1; off >>= 1) s += __shfl_down(s, off);
  if ((tid & 63) == 0) red[tid >> 6] = s;
  __syncthreads();
  if (tid == 0) red[4] = (red[0] + red[1] + red[2] + red[3]) * (1.f / 768.f);
  __syncthreads();
  float mean = red[4];
  float s2 = 0.f;
#pragma unroll
  for (int i = 0; i < 3; i++) { float t = v[i] - mean; s2 += t * t; }
  for (int off = 32; off >= 1; off >>= 1) s2 += __shfl_down(s2, off);
  if ((tid & 63) == 0) red[tid >> 6] = s2;
  __syncthreads();
  if (tid == 0) red[5] = rsqrtf((red[0] + red[1] + red[2] + red[3]) * (1.f / 768.f) + 1e-5f);
  __syncthreads();
  float rstd = red[5];
#pragma unroll
  for (int i = 0; i < 3; i++) {
    int k = tid + i * 256;
    float y = (v[i] - mean) * rstd * g[k] + b[k];
    x[base + k] = y; xb[base + k] = f2bf(y);
  }
}

__global__ __launch_bounds__(256) void embed_kernel(
    const int* __restrict__ idx, const float* __restrict__ tok, const float* __restrict__ pos,
    float* __restrict__ x, u16* __restrict__ xb)
{
  long row = blockIdx.x;
  int t = (int)(row & 1023);
  long tk = idx[row];
  for (int i = threadIdx.x; i < 768; i += 256) {
    float v = tok[tk * 768 + i] + pos[(long)t * 768 + i];
    x[row * 768 + i] = v;
    xb[row * 768 + i] = f2bf(v);
  }
}

extern "C" void kernel_launch(void* const* d_in, const int* in_sizes, int n_in,
                              void* d_out, int out_size, void* d_ws, size_t ws_size,
                              hipStream_t stream)
{
  const int Bb = 2, T = 1024, D = 768, H = 12, L = 6, V = 50257, HS = 64,
            M = 2048, DFF = 3072, NQ = 2304, VP = 50304;
  const int*   idx     = (const int*)d_in[0];
  const float* tok_emb = (const float*)d_in[1];
  const float* pos_emb = (const float*)d_in[2];
  const float* wq      = (const float*)d_in[3];
  const float* wk      = (const float*)d_in[4];
  const float* wv      = (const float*)d_in[5];
  const float* wproj   = (const float*)d_in[6];
  const float* bproj   = (const float*)d_in[7];
  const float* w1      = (const float*)d_in[8];
  const float* b1      = (const float*)d_in[9];
  const float* w2      = (const float*)d_in[10];
  const float* b2      = (const float*)d_in[11];
  const float* ln1g    = (const float*)d_in[12];
  const float* ln1b    = (const float*)d_in[13];
  const float* ln2g    = (const float*)d_in[14];
  const float* ln2b    = (const float*)d_in[15];
  const float* lmw     = (const float*)d_in[16];
  const float* lmb     = (const float*)d_in[17];
  float* out = (float*)d_out;
  (void)in_sizes; (void)n_in; (void)out_size; (void)ws_size;

  char* ws = (char*)d_ws;
  size_t off = 0;
  auto alloc = [&](size_t bytes) -> char* {
    char* p = ws + off; off += (bytes + 255) & ~(size_t)255; return p;
  };
  // persistent across whole call:
  u16* wqkv_t  = (u16*)alloc((size_t)L * NQ * D * 2);
  u16* wproj_t = (u16*)alloc((size_t)L * D * D * 2);
  u16* w1_t    = (u16*)alloc((size_t)L * DFF * D * 2);
  u16* w2_t    = (u16*)alloc((size_t)L * D * DFF * 2);
  float* x     = (float*)alloc((size_t)M * D * 4);
  u16* xb      = (u16*)alloc((size_t)M * D * 2);
  // per-layer scratch (dead by LM-head time):
  char* scratch_base = ws + off;
  u16* qkv     = (u16*)alloc((size_t)M * NQ * 2);
  u16* attn    = (u16*)alloc((size_t)M * D * 2);
  float* tmp   = (float*)alloc((size_t)M * D * 4);
  u16* h1      = (u16*)alloc((size_t)M * DFF * 2);
  // LM-head weight aliases the dead scratch; ensure the region is big enough
  u16* lmw_t   = (u16*)scratch_base;
  {
    size_t scr_off = (size_t)(scratch_base - ws);
    size_t need = (size_t)VP * D * 2;
    if (off - scr_off < need) off = scr_off + need;
  }

  dim3 blk(256);
  // ---- weight downcast-transposes (fp32 -> bf16 [N,K] "Bt" form) ----
  {
    long sS1 = (long)H * D * HS, sS2 = (long)D * HS;
    long dS1 = (long)NQ * D,     dS2 = (long)HS * D;
    transpose_f2b<<<dim3(2, 24, L * H), blk, 0, stream>>>(wq, wqkv_t,                     D, HS, HS, D, HS, H, sS1, sS2, dS1, dS2);
    transpose_f2b<<<dim3(2, 24, L * H), blk, 0, stream>>>(wk, wqkv_t + (size_t)D * D,     D, HS, HS, D, HS, H, sS1, sS2, dS1, dS2);
    transpose_f2b<<<dim3(2, 24, L * H), blk, 0, stream>>>(wv, wqkv_t + (size_t)2 * D * D, D, HS, HS, D, HS, H, sS1, sS2, dS1, dS2);
    transpose_f2b<<<dim3(24, 24, L), blk, 0, stream>>>(wproj, wproj_t, D, D, D, D, D, 1, (long)D * D, 0, (long)D * D, 0);
    transpose_f2b<<<dim3(96, 24, L), blk, 0, stream>>>(w1, w1_t, D, DFF, DFF, D, DFF, 1, (long)D * DFF, 0, (long)DFF * D, 0);
    transpose_f2b<<<dim3(24, 96, L), blk, 0, stream>>>(w2, w2_t, DFF, D, D, DFF, D, 1, (long)DFF * D, 0, (long)D * DFF, 0);
  }
  embed_kernel<<<dim3(M), blk, 0, stream>>>(idx, tok_emb, pos_emb, x, xb);

  for (int l = 0; l < L; l++) {
    // QKV (no bias)
    gemm_bt<<<dim3(NQ / 128, M / 128, 1), blk, 0, stream>>>(
        xb, wqkv_t + (size_t)l * NQ * D, qkv, M, NQ, D, D, D, NQ,
        1, 0, 0, 0, 0, 0, 0, nullptr, 1.f, 0);
    // fused causal attention: qkv -> attn
    flash_attn<<<dim3(T / 64, Bb * H), blk, 0, stream>>>(qkv, attn);
    // proj (+bias) -> fp32 tmp
    gemm_bt<<<dim3(D / 128, M / 128, 1), blk, 0, stream>>>(
        attn, wproj_t + (size_t)l * D * D, tmp, M, D, D, D, D, D,
        1, 0, 0, 0, 0, 0, 0, bproj + (size_t)l * D, 1.f, FLAG_OUTF32);
    add_ln<<<dim3(M), blk, 0, stream>>>(x, tmp, ln1g + (size_t)l * D, ln1b + (size_t)l * D, xb);
    // fc1 (+bias, relu) -> bf16 h1
    gemm_bt<<<dim3(DFF / 128, M / 128, 1), blk, 0, stream>>>(
        xb, w1_t + (size_t)l * DFF * D, h1, M, DFF, D, D, D, DFF,
        1, 0, 0, 0, 0, 0, 0, b1 + (size_t)l * DFF, 1.f, FLAG_RELU);
    // fc2 (+bias) -> fp32 tmp
    gemm_bt<<<dim3(D / 128, M / 128, 1), blk, 0, stream>>>(
        h1, w2_t + (size_t)l * D * DFF, tmp, M, D, DFF, DFF, DFF, D,
        1, 0, 0, 0, 0, 0, 0, b2 + (size_t)l * D, 1.f, FLAG_OUTF32);
    add_ln<<<dim3(M), blk, 0, stream>>>(x, tmp, ln2g + (size_t)l * D, ln2b + (size_t)l * D, xb);
  }
  // LM-head weight transpose into dead scratch ([D,V] fp32 -> [VP,D] bf16, zero-padded rows)
  transpose_f2b<<<dim3(1572, 24, 1), blk, 0, stream>>>(lmw, lmw_t, D, V, V, D, VP, 1, 0, 0, 0, 0);
  // LM head -> fp32 logits
  gemm_bt<<<dim3(VP / 128, M / 128, 1), blk, 0, stream>>>(
      xb, lmw_t, out, M, V, D, D, D, V,
      1, 0, 0, 0, 0, 0, 0, lmb, 1.f, FLAG_OUTF32);
}